// Round 13
// baseline (115.798 us; speedup 1.0000x reference)
//
#include <hip/hip_runtime.h>
#include <math.h>

#define HH 512
#define WW 512
#define HB 64       // band height (8 bands per plane -> grid 992)
#define KR 4        // output rows per group
#define SUB 138     // float4 slots per sub-array; 138%8==2 -> conflict-free
#define ROWF4 (4 * SUB)   // 552 float4 per row
#define TILE (KR * ROWF4) // float4 per buffer

// R13: R12 (reg-ring prefetch, conflict-free imm-offset LDS, light barriers)
// + double-buffered tile -> ONE barrier per group instead of two:
//   group i stages into buf[i&1], H-reads buf[i&1] after the barrier; the
//   buffer being overwritten (reuse distance 2) is protected by the previous
//   barrier (all H_{i-2} reads data-complete before their wave passes
//   BAR_{i-1}, which precedes any stage_i write). Waves flow H->V->stage
//   without block-wide lockstep at the vertical/stage boundary.
// Group loop unrolled x2 so the buffer index is compile-time (ds offsets
// stay immediates). LDS 70.7 KB -> still 2 blocks/CU.

typedef float v2f __attribute__((ext_vector_type(2)));

__device__ __forceinline__ void bar_lgkm() {
  asm volatile("s_waitcnt lgkmcnt(0)" ::: "memory");
  __builtin_amdgcn_s_barrier();
  __builtin_amdgcn_sched_barrier(0);
}

__global__ __launch_bounds__(512, 1)
void ssim_main(const float* __restrict__ Pg, const float* __restrict__ Tg,
               float* __restrict__ partial) {
  __shared__ __align__(16) float4 S4[2 * TILE];   // 70656 B
  __shared__ float wsum[8];

  const int tid = threadIdx.x;            // vertical pass: column 0..511
  const int blk = blockIdx.x;
  const int plane = blk >> 3;
  const int band  = blk & 7;
  const int o0 = band * HB;               // first output row of band
  const float* __restrict__ P = Pg + (size_t)plane * (HH * WW);
  const float* __restrict__ T = Tg + (size_t)plane * (HH * WW);

  // zero both buffers once: halo slots must stay 0 forever; interior is
  // fully overwritten every group.
  {
    const float4 z = make_float4(0.f, 0.f, 0.f, 0.f);
    for (int idx = tid; idx < 2 * TILE; idx += 512) S4[idx] = z;
  }

  // Gaussian weights, computed in double then rounded to f32 (matches jnp f32)
  float w[11];
  {
    double g[11], s = 0.0;
#pragma unroll
    for (int k = 0; k < 11; ++k) {
      double c = (double)(k - 5);
      g[k] = exp(-c * c / 4.5);
      s += g[k];
    }
#pragma unroll
    for (int k = 0; k < 11; ++k)
      w[k] = __uint_as_float(__builtin_amdgcn_readfirstlane(
                 __float_as_uint((float)(g[k] / s))));
  }

  float sum = 0.f;
  const int jr = tid >> 7;                // H-pass: row within group (0..3)
  const int q  = tid & 127;               // H-pass: 4-col block (cols 4q..4q+3)
  // per-thread fixed LDS bases (all tap/write offsets are immediates)
  float4* const rdbase = &S4[jr * ROWF4 + q + 2];
  float4* const wrbase = &S4[(tid & 3) * SUB + (tid >> 2) + 2];

  // ---- register ring: pr/tr[i] = input row rbase+i (i=0..9); pn/tn = rows
  // rbase+10..13 in flight. rbase = o0 + g - 5.
  float pr[10], tr[10], pn[4], tn[4];
#pragma unroll
  for (int i = 0; i < 10; ++i) {
    const int r = o0 - 5 + i;
    const bool v = (r >= 0);              // r <= o0+4 <= 452 < HH always
    pr[i] = v ? P[(size_t)r * WW + tid] : 0.f;
    tr[i] = v ? T[(size_t)r * WW + tid] : 0.f;
  }
#pragma unroll
  for (int i = 0; i < 4; ++i) {
    const int r = o0 + 5 + i;             // always in [5, 461]
    pn[i] = P[(size_t)r * WW + tid];
    tn[i] = T[(size_t)r * WW + tid];
  }

  bar_lgkm();   // zero-init visible before any stage write (stage_0 now
                // precedes the first in-loop barrier)

#define VACC(RI, PV, TV) {                                                 \
      const float p_ = (PV), t_ = (TV);                                   \
      const v2f pt  = {p_, t_};                                           \
      const v2f q23 = {fmaf(t_, t_, p_ * p_), p_ * t_};                   \
      _Pragma("unroll")                                                   \
      for (int j = 0; j < KR; ++j) {                                      \
        if ((RI) - j >= 0 && (RI) - j <= 10) {                            \
          const float wk = w[(RI) - j];                                   \
          const v2f wv = {wk, wk};                                        \
          apt[j] = __builtin_elementwise_fma(wv, pt,  apt[j]);            \
          asq[j] = __builtin_elementwise_fma(wv, q23, asq[j]);            \
        }                                                                 \
      }                                                                   \
    }

#define GROUP(G, B) {                                                      \
    /* vertical pass: pure register math, packed accumulators */           \
    v2f apt[KR], asq[KR];                                                  \
    {                                                                      \
      const v2f z = {0.f, 0.f};                                            \
      _Pragma("unroll")                                                    \
      for (int j = 0; j < KR; ++j) { apt[j] = z; asq[j] = z; }             \
    }                                                                      \
    _Pragma("unroll")                                                      \
    for (int ri = 0; ri < 10; ++ri) VACC(ri, pr[ri], tr[ri]);              \
    _Pragma("unroll")                                                      \
    for (int i = 0; i < 4; ++i) VACC(10 + i, pn[i], tn[i]);                \
    /* rotate ring by 4, issue next group's 4-row prefetch */              \
    _Pragma("unroll")                                                      \
    for (int i = 0; i < 6; ++i) { pr[i] = pr[i + 4]; tr[i] = tr[i + 4]; }  \
    _Pragma("unroll")                                                      \
    for (int i = 0; i < 4; ++i) { pr[6 + i] = pn[i]; tr[6 + i] = tn[i]; }  \
    _Pragma("unroll")                                                      \
    for (int i = 0; i < 4; ++i) {                                          \
      const int r = o0 + (G) + 9 + i;                                      \
      if (r < HH) {                                                        \
        pn[i] = P[(size_t)r * WW + tid];                                   \
        tn[i] = T[(size_t)r * WW + tid];                                   \
      } else {                                                             \
        pn[i] = 0.f; tn[i] = 0.f;                                          \
      }                                                                    \
    }                                                                      \
    /* stage into buffer B (other buffer still being read is fine) */      \
    _Pragma("unroll")                                                      \
    for (int j = 0; j < KR; ++j)                                           \
      wrbase[(B) * TILE + j * ROWF4] =                                     \
          make_float4(apt[j][0], apt[j][1], asq[j][0], asq[j][1]);         \
    bar_lgkm();        /* single barrier: stage_B visible to all waves */  \
    /* horizontal pass + SSIM: 4 cols/thread, 14 imm-offset taps */        \
    v2f hpt[4], hsq[4];                                                    \
    {                                                                      \
      const v2f z = {0.f, 0.f};                                            \
      _Pragma("unroll")                                                    \
      for (int m = 0; m < 4; ++m) { hpt[m] = z; hsq[m] = z; }              \
    }                                                                      \
    _Pragma("unroll")                                                      \
    for (int k = 0; k < 14; ++k) {                                         \
      const int d = k - 5;                                                 \
      const int s = d & 3;                                                 \
      const int o = (d - s) >> 2;                                          \
      const float4 v4 = rdbase[(B) * TILE + s * SUB + o];                  \
      const v2f lo = {v4.x, v4.y};                                         \
      const v2f hi = {v4.z, v4.w};                                         \
      _Pragma("unroll")                                                    \
      for (int m = 0; m < 4; ++m) {                                        \
        if (k - m >= 0 && k - m <= 10) {                                   \
          const float wk = w[k - m];                                       \
          const v2f wv = {wk, wk};                                         \
          hpt[m] = __builtin_elementwise_fma(wv, lo, hpt[m]);              \
          hsq[m] = __builtin_elementwise_fma(wv, hi, hsq[m]);              \
        }                                                                  \
      }                                                                    \
      if (k == 7) __builtin_amdgcn_sched_barrier(0);                       \
    }                                                                      \
    _Pragma("unroll")                                                      \
    for (int m = 0; m < 4; ++m) {                                          \
      const float hmp = hpt[m][0], hmt = hpt[m][1];                        \
      const float mp2 = hmp * hmp, mt2 = hmt * hmt, mct = hmp * hmt;       \
      const float ssum = fmaxf(hsq[m][0] - mp2 - mt2, 0.f);                \
      const float scv = hsq[m][1] - mct;                                   \
      const float num = fmaf(2.f, mct, 1.0e-4f) * fmaf(2.f, scv, 9.0e-4f); \
      const float den = (mp2 + mt2 + 1.0e-4f) * (ssum + 9.0e-4f);          \
      sum += num * __builtin_amdgcn_rcpf(den);                             \
    }                                                                      \
  }

  for (int g = 0; g < HB; g += 2 * KR) {  // 8 iterations x 2 groups
    GROUP(g, 0)
    GROUP(g + KR, 1)
  }
#undef GROUP
#undef VACC

  // block reduction of ssim partial sum
#pragma unroll
  for (int off = 32; off > 0; off >>= 1) sum += __shfl_down(sum, off, 64);
  if ((tid & 63) == 0) wsum[tid >> 6] = sum;
  __syncthreads();
  if (tid == 0) {
    float s = 0.f;
#pragma unroll
    for (int k2 = 0; k2 < 8; ++k2) s += wsum[k2];
    partial[blk] = s;
  }
}

__global__ void ssim_fin(const float* __restrict__ partial,
                         float* __restrict__ out, int n) {
  __shared__ double ws[4];
  double s = 0.0;
  for (int idx = threadIdx.x; idx < n; idx += 256) s += (double)partial[idx];
#pragma unroll
  for (int off = 32; off > 0; off >>= 1) s += __shfl_down(s, off, 64);
  if ((threadIdx.x & 63) == 0) ws[threadIdx.x >> 6] = s;
  __syncthreads();
  if (threadIdx.x == 0) {
    double tt = ws[0] + ws[1] + ws[2] + ws[3];
    out[0] = (float)(1.0 - tt / 32505856.0);
  }
}

extern "C" void kernel_launch(void* const* d_in, const int* in_sizes, int n_in,
                              void* d_out, int out_size, void* d_ws, size_t ws_size,
                              hipStream_t stream) {
  const float* pred = (const float*)d_in[0];
  const float* tgt  = (const float*)d_in[1];
  float* out        = (float*)d_out;
  float* partial    = (float*)d_ws;   // 992 floats of scratch

  ssim_main<<<dim3(992), dim3(512), 0, stream>>>(pred, tgt, partial);
  ssim_fin<<<dim3(1), dim3(256), 0, stream>>>(partial, out, 992);
}